// Round 2
// baseline (335.867 us; speedup 1.0000x reference)
//
#include <hip/hip_runtime.h>

// LIF scan: mem = 0.25*mem + x[t]; spk = (mem >= 1); mem -= spk.
// x: [T=100, 32, 16384] f32. Parallel over N=524288 neurons, sequential in T.
// Memory-bound: 420 MB kernel traffic, floor ~67us @ 6.4 TB/s pure-stream.
//
// History: R1 float4/8w/4deep=338 | R3 float2/16w/10deep=334 | R4 float1/32w=345
// | R5 +nontemporal ld+st=328.3 | R6 +2-buf SW pipeline=331.3 (neutral).
// Six variants within +-3% -> kernel insensitive to vector width / waves /
// MLP depth / pipelining. Profile: top-5 dispatches are all 839MB poison
// fills @ ~128us (6.5 TB/s); lif_kernel < 127us (not in top-5).
// R7 theory (last H1 candidate): nt STORES bypass L2 -> 512B write bursts
// interleave with reads at DRAM -> per-channel r/w bus turnaround tax.
// Regular stores let the 4MB/XCD L2 absorb the write stream and drain it in
// large bursts. Reads stay nt (touch-once; keep L2 free for write buffering).
// If neutral again -> kernel is at mixed-stream roofline (~75us), dur_us is
// harness-fill dominated -> declare ROOFLINE.

constexpr int T = 100;
constexpr int N = 32 * 16384;      // 524288 neurons
constexpr int NV2 = N / 2;         // 262144 float2 columns
constexpr int CH = 10;             // loads in flight per buffer; T = 10 chunks

typedef float v2f __attribute__((ext_vector_type(2)));  // builtin-compatible float2

__device__ __forceinline__ void lif_steps(v2f& mem, const v2f* xs, v2f* __restrict__ op,
                                          int c) {
#pragma unroll
    for (int k = 0; k < CH; ++k) {
        const v2f xt = xs[k];
        v2f s;
        // __fmul_rn/__fadd_rn: match numpy's separate mul+add bit-exactly
        // (no FMA contraction) — hard threshold makes ulp drift cascade.
        mem.x = __fadd_rn(__fmul_rn(0.25f, mem.x), xt.x);
        mem.y = __fadd_rn(__fmul_rn(0.25f, mem.y), xt.y);
        s.x = (mem.x >= 1.0f) ? 1.0f : 0.0f;
        s.y = (mem.y >= 1.0f) ? 1.0f : 0.0f;
        mem.x -= s.x;
        mem.y -= s.y;
        op[(size_t)(c + k) * NV2] = s;   // REGULAR store: allocate in L2,
                                         // drain to DRAM in large bursts
    }
}

__global__ __launch_bounds__(256) void lif_kernel(const v2f* __restrict__ x,
                                                  v2f* __restrict__ out) {
    const int i = blockIdx.x * 256 + threadIdx.x;   // float2 column index
    const v2f* xp = x + i;
    v2f* op = out + i;

    v2f mem = {0.f, 0.f};
    v2f xa[CH], xb[CH];

    // Prologue: fill buffer A with chunk 0.
#pragma unroll
    for (int k = 0; k < CH; ++k)
        xa[k] = __builtin_nontemporal_load(xp + (size_t)k * NV2);

    // Steady state: (load B | compute A) then (load A | compute B), 5 iters.
    for (int c = 0; c < T; c += 2 * CH) {
#pragma unroll
        for (int k = 0; k < CH; ++k)
            xb[k] = __builtin_nontemporal_load(xp + (size_t)(c + CH + k) * NV2);

        lif_steps(mem, xa, op, c);

        if (c + 2 * CH < T) {
#pragma unroll
            for (int k = 0; k < CH; ++k)
                xa[k] = __builtin_nontemporal_load(xp + (size_t)(c + 2 * CH + k) * NV2);
        }

        lif_steps(mem, xb, op, c + CH);
    }
}

extern "C" void kernel_launch(void* const* d_in, const int* in_sizes, int n_in,
                              void* d_out, int out_size, void* d_ws, size_t ws_size,
                              hipStream_t stream) {
    const v2f* x = (const v2f*)d_in[0];
    v2f* out = (v2f*)d_out;
    const int blocks = NV2 / 256;   // 1024 -> 4 blocks/CU, 16 waves/CU
    lif_kernel<<<blocks, 256, 0, stream>>>(x, out);
}